// Round 7
// baseline (1034.013 us; speedup 1.0000x reference)
//
#include <hip/hip_runtime.h>
#include <hip/hip_bf16.h>
#include <hip/hip_cooperative_groups.h>
#include <math.h>

namespace cg = cooperative_groups;

// x: [D=32, N=9216] fp32. 3 iters: w(i,j)=exp(3*<x_i,x_j>),
// x[:,j] <- 0.5*sum_i w*x[:,i]/sum_i w + 0.5*x[:,j]
// Output: [x3][x1][x2][x3].
// R7: barrier-free accum (direct-global MFMA fragments, sigma-permutation in
// addressing, register double-buffer). Cooperative single-kernel if the
// runtime accepts it; error-checked fallback to multi-launch (same phases).

#define D 32
#define NPIX 9216
#define NSPLIT 16            // i-split
#define JB 128               // j per block = 2 waves * 64 j
#define NJB 72               // NPIX/JB
#define IPB 576              // NPIX/NSPLIT
#define NBLK 1152            // NJB*NSPLIT
#define NTHR 128
#define IOWN 8               // NPIX/NBLK: i owned per block in setup/combine

typedef __attribute__((ext_vector_type(8))) short short8;
typedef __attribute__((ext_vector_type(2))) short short2v;
typedef __attribute__((ext_vector_type(4))) float f32x4;

#if __has_builtin(__builtin_amdgcn_exp2f)
#define EXP2F __builtin_amdgcn_exp2f
#else
#define EXP2F exp2f
#endif

#define C3 4.32808512266689f   // 3 * log2(e)

__device__ __forceinline__ unsigned pack2_bf16(float a, float b) {
    union { __hip_bfloat162 h2; unsigned u; } c;
    c.h2 = __float22bfloat162_rn(make_float2(a, b));
    return c.u;
}
__device__ __forceinline__ short pack1_bf16(float a) {
    union { __hip_bfloat16 h; unsigned short s; } c;
    c.h = __float2bfloat16(a);
    return (short)c.s;
}

// ---------------- phases (shared by coop kernel and fallback kernels) -------

__device__ __forceinline__ void setup_phase(
    int b, int t, const float* __restrict__ x0,
    short* __restrict__ xb, short* __restrict__ xbT, short* tile)
{
    const int il = t & 7, dg = t >> 3;          // il 0..7, dg 0..15
    const int i = b * IOWN + il;
#pragma unroll
    for (int h = 0; h < 2; ++h) {
        const int d = dg + h * 16;
        short bb = pack1_bf16(x0[d * NPIX + i]);
        xb[d * NPIX + i] = bb;
        tile[il * 36 + d] = bb;
    }
    __syncthreads();
    const int r = t >> 4, c2 = (t & 15) * 2;    // r 0..7
    *(short2v*)&xbT[(size_t)(b * IOWN + r) * D + c2] = *(const short2v*)&tile[r * 36 + c2];
}

__device__ __forceinline__ void accum_phase(
    int b, int t, const short* __restrict__ xb, const short* __restrict__ xbT,
    float* __restrict__ num_part, float* __restrict__ den_part)
{
    const int wid = t >> 6, lane = t & 63, quad = lane >> 4, m = lane & 15;
    const int bj = b % NJB, bi = b / NJB;
    const int j0 = bj * JB + wid * 64;
    const int i0b = bi * IPB;

    // QK B-frags (j side): B[k=d][n=j_local]; lane: n=m, k=quad*8+e
    short8 bfrag[4];
#pragma unroll
    for (int jt = 0; jt < 4; ++jt)
        bfrag[jt] = *(const short8*)&xbT[(size_t)(j0 + jt * 16 + m) * D + quad * 8];

    f32x4 acc[2][4] = {};                 // [d-tile][j-tile], C-layout
    float dacc[4] = {0.f, 0.f, 0.f, 0.f};

    // sigma^-1(m): QK A-row m holds x_{i0 + sinv}; row 16+m -> +4.
    const int sinv = ((m & 12) << 1) | (m & 3);
    const short* pT = xbT + (size_t)(i0b + sinv) * D + quad * 8;   // +4*D: aT1
    const short* pV = xb + (size_t)m * NPIX + i0b + quad * 8;      // +16*NPIX: aV1

    short8 cT0 = *(const short8*)pT;
    short8 cT1 = *(const short8*)(pT + 4 * D);
    short8 cV0 = *(const short8*)pV;
    short8 cV1 = *(const short8*)(pV + 16 * NPIX);

    for (int c = 0; c < IPB / 32; ++c) {
        short8 nT0 = cT0, nT1 = cT1, nV0 = cV0, nV1 = cV1;
        if (c + 1 < IPB / 32) {
            const short* qT = pT + (size_t)(c + 1) * 32 * D;
            const short* qV = pV + (c + 1) * 32;
            nT0 = *(const short8*)qT;
            nT1 = *(const short8*)(qT + 4 * D);
            nV0 = *(const short8*)qV;
            nV1 = *(const short8*)(qV + 16 * NPIX);
        }
#pragma unroll
        for (int jt = 0; jt < 4; ++jt) {
            f32x4 z = {0.f, 0.f, 0.f, 0.f};
            // s0 regs r: S[i_local=quad*8+r][j=m]; s1: +4 (sigma trick)
            f32x4 s0 = __builtin_amdgcn_mfma_f32_16x16x32_bf16(cT0, bfrag[jt], z, 0, 0, 0);
            f32x4 s1 = __builtin_amdgcn_mfma_f32_16x16x32_bf16(cT1, bfrag[jt], z, 0, 0, 0);

            float w[8];
#pragma unroll
            for (int r = 0; r < 4; ++r) { w[r]     = EXP2F(C3 * s0[r]);
                                          w[4 + r] = EXP2F(C3 * s1[r]); }
            float p0 = (w[0] + w[1]) + (w[2] + w[3]);
            float p1 = (w[4] + w[5]) + (w[6] + w[7]);
            dacc[jt] += p0 + p1;

            // In-register PV B-frag: element e = i_local quad*8+e
            union { short8 s; unsigned u[4]; } wb;
            wb.u[0] = pack2_bf16(w[0], w[1]);
            wb.u[1] = pack2_bf16(w[2], w[3]);
            wb.u[2] = pack2_bf16(w[4], w[5]);
            wb.u[3] = pack2_bf16(w[6], w[7]);

            acc[0][jt] = __builtin_amdgcn_mfma_f32_16x16x32_bf16(cV0, wb.s, acc[0][jt], 0, 0, 0);
            acc[1][jt] = __builtin_amdgcn_mfma_f32_16x16x32_bf16(cV1, wb.s, acc[1][jt], 0, 0, 0);
        }
        cT0 = nT0; cT1 = nT1; cV0 = nV0; cV1 = nV1;
    }

    // partial stores (each element written exactly once; nothing pre-zeroed)
    float* np = num_part + (size_t)bi * D * NPIX;
#pragma unroll
    for (int dt = 0; dt < 2; ++dt)
#pragma unroll
        for (int jt = 0; jt < 4; ++jt)
#pragma unroll
            for (int r = 0; r < 4; ++r)
                np[(dt * 16 + quad * 4 + r) * NPIX + j0 + jt * 16 + m] = acc[dt][jt][r];
#pragma unroll
    for (int jt = 0; jt < 4; ++jt) {
        float v = dacc[jt];
        v += __shfl_xor(v, 16, 64);
        v += __shfl_xor(v, 32, 64);
        if (quad == 0) den_part[bi * NPIX + j0 + jt * 16 + m] = v;
    }
}

__device__ __forceinline__ void combine_phase(
    int b, int t, int it, const float* __restrict__ x0, float* __restrict__ out,
    const float* __restrict__ num_part, const float* __restrict__ den_part,
    short* __restrict__ xb, short* __restrict__ xbT, short* tile)
{
    const size_t slot = (size_t)D * NPIX;
    const int il = t & 7, dg = t >> 3;
    const int i = b * IOWN + il;

    float ds = 0.f;
#pragma unroll
    for (int s = 0; s < NSPLIT; ++s) ds += den_part[s * NPIX + i];
    const float inv = 0.5f / ds;

    const float* xin = (it == 0) ? x0 : out + (size_t)it * slot;
    float* xout = out + (size_t)(it + 1) * slot;

#pragma unroll
    for (int h = 0; h < 2; ++h) {
        const int d = dg + h * 16;
        const int idx = d * NPIX + i;
        float nm = 0.f;
#pragma unroll
        for (int s = 0; s < NSPLIT; ++s) nm += num_part[(s * D + d) * NPIX + i];
        float v = nm * inv + 0.5f * xin[idx];
        xout[idx] = v;
        if (it == 2) out[idx] = v;
        short bb = pack1_bf16(v);
        xb[idx] = bb;
        tile[il * 36 + d] = bb;
    }
    __syncthreads();
    const int r = t >> 4, c2 = (t & 15) * 2;
    *(short2v*)&xbT[(size_t)(b * IOWN + r) * D + c2] = *(const short2v*)&tile[r * 36 + c2];
}

// ---------------- cooperative single-kernel path ----------------------------

__global__ __launch_bounds__(NTHR, 3) void ms_kernel(
    const float* __restrict__ x0, float* __restrict__ out,
    float* __restrict__ num_part, float* __restrict__ den_part,
    short* __restrict__ xb, short* __restrict__ xbT)
{
    cg::grid_group grid = cg::this_grid();
    __shared__ __align__(8) short tile[IOWN * 36];
    const int t = threadIdx.x, b = blockIdx.x;

    setup_phase(b, t, x0, xb, xbT, tile);
    grid.sync();
    for (int it = 0; it < 3; ++it) {
        accum_phase(b, t, xb, xbT, num_part, den_part);
        grid.sync();
        combine_phase(b, t, it, x0, out, num_part, den_part, xb, xbT, tile);
        if (it < 2) grid.sync();
    }
}

// ---------------- fallback multi-launch path --------------------------------

__global__ __launch_bounds__(NTHR, 3) void setup_kernel(
    const float* __restrict__ x0, short* __restrict__ xb, short* __restrict__ xbT)
{
    __shared__ __align__(8) short tile[IOWN * 36];
    setup_phase(blockIdx.x, threadIdx.x, x0, xb, xbT, tile);
}

__global__ __launch_bounds__(NTHR, 3) void accum_kernel(
    const short* __restrict__ xb, const short* __restrict__ xbT,
    float* __restrict__ num_part, float* __restrict__ den_part)
{
    accum_phase(blockIdx.x, threadIdx.x, xb, xbT, num_part, den_part);
}

__global__ __launch_bounds__(NTHR, 3) void combine_kernel(
    const float* __restrict__ x0, float* __restrict__ out,
    const float* __restrict__ num_part, const float* __restrict__ den_part,
    short* __restrict__ xb, short* __restrict__ xbT, int it)
{
    __shared__ __align__(8) short tile[IOWN * 36];
    combine_phase(blockIdx.x, threadIdx.x, it, x0, out, num_part, den_part, xb, xbT, tile);
}

extern "C" void kernel_launch(void* const* d_in, const int* in_sizes, int n_in,
                              void* d_out, int out_size, void* d_ws, size_t ws_size,
                              hipStream_t stream)
{
    const float* x0 = (const float*)d_in[0];
    float* out = (float*)d_out;              // [x3][x1][x2][x3]
    const size_t slot = (size_t)D * NPIX;

    float* num_part = (float*)d_ws;                          // 18.9 MB
    float* den_part = num_part + (size_t)NSPLIT * slot;      // 590 KB
    short* xb  = (short*)(den_part + (size_t)NSPLIT * NPIX); // 590 KB
    short* xbT = xb + slot;                                  // 590 KB

    void* args[] = { (void*)&x0, (void*)&out, (void*)&num_part,
                     (void*)&den_part, (void*)&xb, (void*)&xbT };
    hipError_t e = hipLaunchCooperativeKernel((const void*)ms_kernel,
                                              dim3(NBLK), dim3(NTHR),
                                              args, 0, stream);
    if (e != hipSuccess) {
        // fallback: same phases, separate launches (no grid.sync needed)
        setup_kernel<<<dim3(NBLK), dim3(NTHR), 0, stream>>>(x0, xb, xbT);
        for (int it = 0; it < 3; ++it) {
            accum_kernel<<<dim3(NBLK), dim3(NTHR), 0, stream>>>(xb, xbT, num_part, den_part);
            combine_kernel<<<dim3(NBLK), dim3(NTHR), 0, stream>>>(
                x0, out, num_part, den_part, xb, xbT, it);
        }
    }
}

// Round 8
// 204.507 us; speedup vs baseline: 5.0561x; 5.0561x over previous
//
#include <hip/hip_runtime.h>
#include <hip/hip_bf16.h>
#include <math.h>

// x: [D=32, N=9216] fp32. 3 iters: w(i,j)=exp(3*<x_i,x_j>),
// x[:,j] <- 0.5*sum_i w*x[:,i]/sum_i w + 0.5*x[:,j]
// Output: [x3][x1][x2][x3].
// R8: multi-launch (NO cooperative sync — grid.sync spin traffic cost ~950us
// in R7). Accum is barrier-free: MFMA A-fragments loaded DIRECTLY from global
// (sigma-permutation folded into addressing), register double-buffered, no LDS.
// Partial-store reduction (no atomics, nothing pre-zeroed).

#define D 32
#define NPIX 9216
#define NSPLIT 16            // i-split
#define JB 128               // j per block = 2 waves * 64 j
#define NJB 72               // NPIX/JB
#define IPB 576              // NPIX/NSPLIT
#define NBLK 1152            // NJB*NSPLIT
#define NTHR 128
#define IOWN 8               // NPIX/NBLK: i owned per block in setup/combine

typedef __attribute__((ext_vector_type(8))) short short8;
typedef __attribute__((ext_vector_type(2))) short short2v;
typedef __attribute__((ext_vector_type(4))) float f32x4;

#if __has_builtin(__builtin_amdgcn_exp2f)
#define EXP2F __builtin_amdgcn_exp2f
#else
#define EXP2F exp2f
#endif

#define C3 4.32808512266689f   // 3 * log2(e)

__device__ __forceinline__ unsigned pack2_bf16(float a, float b) {
    union { __hip_bfloat162 h2; unsigned u; } c;
    c.h2 = __float22bfloat162_rn(make_float2(a, b));
    return c.u;
}
__device__ __forceinline__ short pack1_bf16(float a) {
    union { __hip_bfloat16 h; unsigned short s; } c;
    c.h = __float2bfloat16(a);
    return (short)c.s;
}

// ---------------- setup: x0 -> xb, xbT ---------------------------------------
__global__ __launch_bounds__(NTHR) void setup_kernel(
    const float* __restrict__ x0, short* __restrict__ xb, short* __restrict__ xbT)
{
    __shared__ __align__(8) short tile[IOWN * 36];
    const int t = threadIdx.x, b = blockIdx.x;
    const int il = t & 7, dg = t >> 3;
    const int i = b * IOWN + il;
#pragma unroll
    for (int h = 0; h < 2; ++h) {
        const int d = dg + h * 16;
        short bb = pack1_bf16(x0[d * NPIX + i]);
        xb[d * NPIX + i] = bb;
        tile[il * 36 + d] = bb;
    }
    __syncthreads();
    const int r = t >> 4, c2 = (t & 15) * 2;
    *(short2v*)&xbT[(size_t)(b * IOWN + r) * D + c2] = *(const short2v*)&tile[r * 36 + c2];
}

// ---------------- accum: barrier-free, no LDS --------------------------------
// num_part[bi][d][j] = sum_{i in split bi} w(i,j)*x[d][i]; den_part likewise.
__global__ __launch_bounds__(NTHR) void accum_kernel(
    const short* __restrict__ xb,    // bf16 bits [D][NPIX]
    const short* __restrict__ xbT,   // bf16 bits [NPIX][D]
    float* __restrict__ num_part,    // [NSPLIT][D][NPIX]
    float* __restrict__ den_part)    // [NSPLIT][NPIX]
{
    const int t = threadIdx.x;
    const int wid = t >> 6, lane = t & 63, quad = lane >> 4, m = lane & 15;
    const int bj = blockIdx.x % NJB, bi = blockIdx.x / NJB;
    const int j0 = bj * JB + wid * 64;
    const int i0b = bi * IPB;

    // QK B-frags (j side): B[k=d][n=j_local]; lane: n=m, k=quad*8+e
    short8 bfrag[4];
#pragma unroll
    for (int jt = 0; jt < 4; ++jt)
        bfrag[jt] = *(const short8*)&xbT[(size_t)(j0 + jt * 16 + m) * D + quad * 8];

    f32x4 acc[2][4] = {};                 // [d-tile][j-tile], C-layout
    float dacc[4] = {0.f, 0.f, 0.f, 0.f};

    // sigma^-1(m): QK A-row m holds x_{i0 + sinv}; row 16+m -> +4.
    // => S C-regs land exactly in PV B-fragment layout (i_local = quad*8+e).
    const int sinv = ((m & 12) << 1) | (m & 3);
    const short* pT = xbT + (size_t)(i0b + sinv) * D + quad * 8;   // +4*D: aT1
    const short* pV = xb + (size_t)m * NPIX + i0b + quad * 8;      // +16*NPIX: aV1

    short8 cT0 = *(const short8*)pT;
    short8 cT1 = *(const short8*)(pT + 4 * D);
    short8 cV0 = *(const short8*)pV;
    short8 cV1 = *(const short8*)(pV + 16 * NPIX);

    for (int c = 0; c < IPB / 32; ++c) {
        short8 nT0 = cT0, nT1 = cT1, nV0 = cV0, nV1 = cV1;
        if (c + 1 < IPB / 32) {
            const short* qT = pT + (size_t)(c + 1) * 32 * D;
            const short* qV = pV + (c + 1) * 32;
            nT0 = *(const short8*)qT;
            nT1 = *(const short8*)(qT + 4 * D);
            nV0 = *(const short8*)qV;
            nV1 = *(const short8*)(qV + 16 * NPIX);
        }
#pragma unroll
        for (int jt = 0; jt < 4; ++jt) {
            f32x4 z = {0.f, 0.f, 0.f, 0.f};
            // s0 regs r: S[i_local=quad*8+r][j=m]; s1: +4 (sigma trick)
            f32x4 s0 = __builtin_amdgcn_mfma_f32_16x16x32_bf16(cT0, bfrag[jt], z, 0, 0, 0);
            f32x4 s1 = __builtin_amdgcn_mfma_f32_16x16x32_bf16(cT1, bfrag[jt], z, 0, 0, 0);

            float w[8];
#pragma unroll
            for (int r = 0; r < 4; ++r) { w[r]     = EXP2F(C3 * s0[r]);
                                          w[4 + r] = EXP2F(C3 * s1[r]); }
            float p0 = (w[0] + w[1]) + (w[2] + w[3]);
            float p1 = (w[4] + w[5]) + (w[6] + w[7]);
            dacc[jt] += p0 + p1;

            // In-register PV B-frag: element e = i_local quad*8+e
            union { short8 s; unsigned u[4]; } wb;
            wb.u[0] = pack2_bf16(w[0], w[1]);
            wb.u[1] = pack2_bf16(w[2], w[3]);
            wb.u[2] = pack2_bf16(w[4], w[5]);
            wb.u[3] = pack2_bf16(w[6], w[7]);

            acc[0][jt] = __builtin_amdgcn_mfma_f32_16x16x32_bf16(cV0, wb.s, acc[0][jt], 0, 0, 0);
            acc[1][jt] = __builtin_amdgcn_mfma_f32_16x16x32_bf16(cV1, wb.s, acc[1][jt], 0, 0, 0);
        }
        cT0 = nT0; cT1 = nT1; cV0 = nV0; cV1 = nV1;
    }

    // partial stores (each element written exactly once)
    float* np = num_part + (size_t)bi * D * NPIX;
#pragma unroll
    for (int dt = 0; dt < 2; ++dt)
#pragma unroll
        for (int jt = 0; jt < 4; ++jt)
#pragma unroll
            for (int r = 0; r < 4; ++r)
                np[(dt * 16 + quad * 4 + r) * NPIX + j0 + jt * 16 + m] = acc[dt][jt][r];
#pragma unroll
    for (int jt = 0; jt < 4; ++jt) {
        float v = dacc[jt];
        v += __shfl_xor(v, 16, 64);
        v += __shfl_xor(v, 32, 64);
        if (quad == 0) den_part[bi * NPIX + j0 + jt * 16 + m] = v;
    }
}

// ---------------- combine: reduce partials, emit x_{t+1} ---------------------
__global__ __launch_bounds__(NTHR) void combine_kernel(
    const float* __restrict__ x0, float* __restrict__ out,
    const float* __restrict__ num_part, const float* __restrict__ den_part,
    short* __restrict__ xb, short* __restrict__ xbT, int it)
{
    __shared__ __align__(8) short tile[IOWN * 36];
    const size_t slot = (size_t)D * NPIX;
    const int t = threadIdx.x, b = blockIdx.x;
    const int il = t & 7, dg = t >> 3;
    const int i = b * IOWN + il;

    float ds = 0.f;
#pragma unroll
    for (int s = 0; s < NSPLIT; ++s) ds += den_part[s * NPIX + i];
    const float inv = 0.5f / ds;

    const float* xin = (it == 0) ? x0 : out + (size_t)it * slot;
    float* xout = out + (size_t)(it + 1) * slot;

#pragma unroll
    for (int h = 0; h < 2; ++h) {
        const int d = dg + h * 16;
        const int idx = d * NPIX + i;
        float nm = 0.f;
#pragma unroll
        for (int s = 0; s < NSPLIT; ++s) nm += num_part[(s * D + d) * NPIX + i];
        float v = nm * inv + 0.5f * xin[idx];
        xout[idx] = v;
        if (it == 2) out[idx] = v;
        short bb = pack1_bf16(v);
        xb[idx] = bb;
        tile[il * 36 + d] = bb;
    }
    __syncthreads();
    const int r = t >> 4, c2 = (t & 15) * 2;
    *(short2v*)&xbT[(size_t)(b * IOWN + r) * D + c2] = *(const short2v*)&tile[r * 36 + c2];
}

extern "C" void kernel_launch(void* const* d_in, const int* in_sizes, int n_in,
                              void* d_out, int out_size, void* d_ws, size_t ws_size,
                              hipStream_t stream)
{
    const float* x0 = (const float*)d_in[0];
    float* out = (float*)d_out;              // [x3][x1][x2][x3]
    const size_t slot = (size_t)D * NPIX;

    float* num_part = (float*)d_ws;                          // 18.9 MB
    float* den_part = num_part + (size_t)NSPLIT * slot;      // 590 KB
    short* xb  = (short*)(den_part + (size_t)NSPLIT * NPIX); // 590 KB
    short* xbT = xb + slot;                                  // 590 KB

    setup_kernel<<<dim3(NBLK), dim3(NTHR), 0, stream>>>(x0, xb, xbT);
    for (int it = 0; it < 3; ++it) {
        accum_kernel<<<dim3(NBLK), dim3(NTHR), 0, stream>>>(xb, xbT, num_part, den_part);
        combine_kernel<<<dim3(NBLK), dim3(NTHR), 0, stream>>>(
            x0, out, num_part, den_part, xb, xbT, it);
    }
}